// Round 8
// baseline (838.818 us; speedup 1.0000x reference)
//
#include <hip/hip_runtime.h>
#include <hip/hip_bf16.h>
#include <math.h>

typedef __attribute__((ext_vector_type(8))) short short8;
typedef __attribute__((ext_vector_type(4))) float f32x4;

#define MFMA16(a,b,c) __builtin_amdgcn_mfma_f32_16x16x32_bf16((a),(b),(c),0,0,0)

__device__ __forceinline__ unsigned short f2bf(float f){
  unsigned int u = __builtin_bit_cast(unsigned int, f);
  u += 0x7fffu + ((u >> 16) & 1u);
  return (unsigned short)(u >> 16);
}

__device__ __forceinline__ void gload16(const void* g, void* lds){
  __builtin_amdgcn_global_load_lds(
      (const __attribute__((address_space(1))) unsigned int*)g,
      (__attribute__((address_space(3))) unsigned int*)lds, 16, 0, 0);
}

// ---------------- weight transpose + cast: in [K][N] f32 -> out [N][K] bf16 ----------------
__global__ __launch_bounds__(256) void k_transpose_cast(const float* __restrict__ in,
    unsigned short* __restrict__ out, int K, int N)
{
  __shared__ unsigned short tile[32][33];
  const int tx = threadIdx.x, ty = threadIdx.y;
  const int n0 = blockIdx.x * 32, k0 = blockIdx.y * 32;
  #pragma unroll
  for (int i = 0; i < 4; i++) {
    int k = k0 + ty + i*8;
    tile[ty + i*8][tx] = f2bf(in[(size_t)k * N + n0 + tx]);
  }
  __syncthreads();
  #pragma unroll
  for (int i = 0; i < 4; i++) {
    int n = n0 + ty + i*8;
    out[(size_t)n * K + k0 + tx] = tile[tx][ty + i*8];
  }
}

// ---------------- layernorm: x [rows][1024] f32 -> out bf16 ----------------
__global__ __launch_bounds__(256) void k_layernorm(const float* __restrict__ x,
    const float* __restrict__ g, const float* __restrict__ b,
    unsigned short* __restrict__ out)
{
  const int row = blockIdx.x;
  const int t = threadIdx.x;
  const float4 v = ((const float4*)(x + (size_t)row * 1024))[t];
  float s  = v.x + v.y + v.z + v.w;
  float s2 = v.x*v.x + v.y*v.y + v.z*v.z + v.w*v.w;
  #pragma unroll
  for (int m = 1; m < 64; m <<= 1) {
    s  += __shfl_xor(s,  m);
    s2 += __shfl_xor(s2, m);
  }
  __shared__ float red[2][4];
  const int wid = t >> 6, lane = t & 63;
  if (lane == 0) { red[0][wid] = s; red[1][wid] = s2; }
  __syncthreads();
  s  = red[0][0] + red[0][1] + red[0][2] + red[0][3];
  s2 = red[1][0] + red[1][1] + red[1][2] + red[1][3];
  const float mu = s * (1.0f / 1024.0f);
  const float var = s2 * (1.0f / 1024.0f) - mu * mu;
  const float rstd = rsqrtf(var + 1e-6f);
  const float4 gv = ((const float4*)g)[t];
  const float4 bv = ((const float4*)b)[t];
  ushort4 o;
  o.x = f2bf((v.x - mu) * rstd * gv.x + bv.x);
  o.y = f2bf((v.y - mu) * rstd * gv.y + bv.y);
  o.z = f2bf((v.z - mu) * rstd * gv.z + bv.z);
  o.w = f2bf((v.w - mu) * rstd * gv.w + bv.w);
  ((ushort4*)(out + (size_t)row * 1024))[t] = o;
}

// ---------------- 256x256 MFMA GEMM — m201-style 8-phase schedule ----------------
// C[M][N] = A[M][K](bf16) * Bt[N][K]^T(bf16) + epilogue
// EPI 0: QKV: bn<8 -> qk (stride 2048) bf16; bn>=8 -> vT[b][h][d][n] bf16
// EPI 1: out bf16 = gelu(acc + bias)   EPI 2: out f32 = resid + (acc+bias)*lsg
//
// LDS (bytes): A: buf0h0 [0,16K) buf0h1 [16K,32K) buf1h0 [32K,48K) buf1h1 [48K,64K); B at +64K.
// Staging unit = half-tile (128 rows x 64 k) = 2 gload_lds/thread.
// 8 phases / 2 K-tiles; per phase: {ds_reads (pre-barrier), stage 1 unit, [vmcnt],
//   s_barrier, lgkmcnt(0), sched_barrier, setprio(1), 16 MFMA, setprio(0), s_barrier}.
// Ledger (iter j computes T=2j buf0 @p1-4, T+1 buf1 @p5-8):
//   p1: STG Ah1(T+1)->buf1 | p3: Bh0(T+2)->buf0 | p4: Bh1(T+2)->buf0 + vmcnt(4)
//   p5: Ah0(T+2)->buf0     | p6: Ah1(T+2)->buf0 | p7: Bh0(T+3)->buf1
//   p8: Bh1(T+3)+Ah0(T+3)->buf1 + vmcnt(6)
//   vmcnt(4)@p4 certifies tile T+1 (read from p5); vmcnt(6)@p8 certifies tile T+2
//   (read next iter p1). Prologue = virtual p8: 7 units + vmcnt(6) + barrier.
//   Tail (T+2>=NT): skip p3-p8 stages; p4 -> vmcnt(0).
template<int EPI>
__global__ __launch_bounds__(512, 2) void k_gemm256(
    const unsigned short* __restrict__ A,
    const unsigned short* __restrict__ Bt,
    const float* __restrict__ bias,
    const float* __restrict__ resid,
    const float* __restrict__ lsg,
    void* __restrict__ outp,
    unsigned short* __restrict__ vtp,
    int M, int N, int K, int nbn)
{
  __shared__ __align__(16) char smem[131072];

  // XCD-chunked bijective swizzle
  const int bid = blockIdx.x;
  const int mrows = (gridDim.x >> 3) / nbn;
  const int xcd = bid & 7, l = bid >> 3;
  const int bm = xcd * mrows + (l % mrows);
  const int bn = l / mrows;

  const int t = threadIdx.x, lane = t & 63;
  const int wid = t >> 6, wm = wid >> 2, wn = wid & 3;
  const int fr = lane & 15, fg = lane >> 4;

  // staging addressing: slot s in [0,1024): hr=s>>3, cc=s&7, source chunk cs=cc^(hr&7)
  // thread t owns slots t and 512+t (LDS linear dest, pre-swizzled source — rule #21)
  const int hr0 = t >> 3;
  const int cs0 = ((t & 7) ^ (hr0 & 7)) * 8;
  const int hr1 = (512 + t) >> 3;
  const int cs1 = (((512 + t) & 7) ^ (hr1 & 7)) * 8;
  const size_t aR0 = ((size_t)bm * 256 + hr0) * K + cs0;
  const size_t aR1 = ((size_t)bm * 256 + hr1) * K + cs1;
  const size_t bR0 = ((size_t)bn * 256 + hr0) * K + cs0;
  const size_t bR1 = ((size_t)bn * 256 + hr1) * K + cs1;

#define STG_A(h, bb, X) { \
  gload16(A + aR0 + (size_t)(h)*128*K + (size_t)(X)*64, smem + ((bb)*2+(h))*16384 + t*16); \
  gload16(A + aR1 + (size_t)(h)*128*K + (size_t)(X)*64, smem + ((bb)*2+(h))*16384 + 8192 + t*16); }
#define STG_B(h, bb, X) { \
  gload16(Bt + bR0 + (size_t)(h)*128*K + (size_t)(X)*64, smem + 65536 + ((bb)*2+(h))*16384 + t*16); \
  gload16(Bt + bR1 + (size_t)(h)*128*K + (size_t)(X)*64, smem + 65536 + ((bb)*2+(h))*16384 + 8192 + t*16); }

#define RD_AF(mhq, bb) \
  _Pragma("unroll") \
  for (int m_ = 0; m_ < 4; m_++) { \
    const int rr_ = (mhq)*64 + m_*16 + fr; \
    const char* p_ = smem + ((bb)*2 + wm)*16384 + rr_*128; \
    af[m_*2+0] = *(const short8*)(p_ + ((fg ^ (fr&7))*16)); \
    af[m_*2+1] = *(const short8*)(p_ + (((4+fg) ^ (fr&7))*16)); \
  }
#define RD_BF(nhq, bb, dst) \
  _Pragma("unroll") \
  for (int n_ = 0; n_ < 2; n_++) { \
    const int rr_ = (wn&1)*64 + (nhq)*32 + n_*16 + fr; \
    const char* p_ = smem + 65536 + ((bb)*2 + (wn>>1))*16384 + rr_*128; \
    dst[n_*2+0] = *(const short8*)(p_ + ((fg ^ (fr&7))*16)); \
    dst[n_*2+1] = *(const short8*)(p_ + (((4+fg) ^ (fr&7))*16)); \
  }

#define MMAQ(mhq, nhq, B_) \
  __builtin_amdgcn_s_setprio(1); \
  _Pragma("unroll") \
  for (int kk_ = 0; kk_ < 2; kk_++) \
    _Pragma("unroll") \
    for (int m_ = 0; m_ < 4; m_++) \
      _Pragma("unroll") \
      for (int n_ = 0; n_ < 2; n_++) \
        acc[(mhq)*4+m_][(nhq)*2+n_] = \
            MFMA16(af[m_*2+kk_], B_[n_*2+kk_], acc[(mhq)*4+m_][(nhq)*2+n_]); \
  __builtin_amdgcn_s_setprio(0);

#define PH_SYNC \
  __builtin_amdgcn_s_barrier(); \
  asm volatile("s_waitcnt lgkmcnt(0)" ::: "memory"); \
  __builtin_amdgcn_sched_barrier(0);
#define PH_END __builtin_amdgcn_s_barrier();

  f32x4 acc[8][4] = {};
  short8 af[8], bf0[4], bf1[4];
  const int NT = K >> 6;

  // prologue (virtual p8): tile0 all units + tile1 Bh0,Bh1,Ah0; vmcnt(6)=3 units out
  STG_B(0, 0, 0); STG_B(1, 0, 0); STG_A(0, 0, 0); STG_A(1, 0, 0);
  STG_B(0, 1, 1); STG_B(1, 1, 1); STG_A(0, 1, 1);
  asm volatile("s_waitcnt vmcnt(6)" ::: "memory");
  __builtin_amdgcn_s_barrier();

  for (int j = 0; j < (NT >> 1); ++j) {
    const int T = 2 * j;
    const bool more = (T + 2 < NT);
    // ---- p1: T(buf0) quadrant (0,0) ----
    RD_AF(0, 0); RD_BF(0, 0, bf0);
    STG_A(1, 1, T + 1);
    PH_SYNC; MMAQ(0, 0, bf0); PH_END;
    // ---- p2: (0,1) ----
    RD_BF(1, 0, bf1);
    PH_SYNC; MMAQ(0, 1, bf1); PH_END;
    // ---- p3: (1,0) ----
    RD_AF(1, 0);
    if (more) STG_B(0, 0, T + 2);
    PH_SYNC; MMAQ(1, 0, bf0); PH_END;
    // ---- p4: (1,1) + certify tile T+1 ----
    if (more) {
      STG_B(1, 0, T + 2);
      asm volatile("s_waitcnt vmcnt(4)" ::: "memory");
    } else {
      asm volatile("s_waitcnt vmcnt(0)" ::: "memory");
    }
    PH_SYNC; MMAQ(1, 1, bf1); PH_END;
    // ---- p5: T+1(buf1) quadrant (0,0) ----
    RD_AF(0, 1); RD_BF(0, 1, bf0);
    if (more) STG_A(0, 0, T + 2);
    PH_SYNC; MMAQ(0, 0, bf0); PH_END;
    // ---- p6: (0,1) ----
    RD_BF(1, 1, bf1);
    if (more) STG_A(1, 0, T + 2);
    PH_SYNC; MMAQ(0, 1, bf1); PH_END;
    // ---- p7: (1,0) ----
    RD_AF(1, 1);
    if (more) STG_B(0, 1, T + 3);
    PH_SYNC; MMAQ(1, 0, bf0); PH_END;
    // ---- p8: (1,1) + certify tile T+2 ----
    if (more) {
      STG_B(1, 1, T + 3); STG_A(0, 1, T + 3);
      asm volatile("s_waitcnt vmcnt(6)" ::: "memory");
    }
    PH_SYNC; MMAQ(1, 1, bf1); PH_END;
  }

  // ---- epilogue: direct stores ----
  const int row0 = bm * 256 + wm * 128 + fg * 4;
  const int col0 = bn * 256 + wn * 64 + fr;
  #pragma unroll
  for (int n = 0; n < 4; n++) {
    const int col = col0 + n * 16;
    const float bcol = bias[col];
    float lscale = 0.f;
    if (EPI == 2) lscale = lsg[col];
    #pragma unroll
    for (int m = 0; m < 8; m++) {
      #pragma unroll
      for (int r = 0; r < 4; r++) {
        const int row = row0 + m * 16 + r;
        float v = acc[m][n][r] + bcol;
        if (EPI == 0) {
          if (bn < 8) {
            ((unsigned short*)outp)[(size_t)row * 2048 + col] = f2bf(v);
          } else {
            const int d = col - 2048, hh = d >> 6, dd = d & 63;
            const int bb = row >> 10, nn = row & 1023;
            vtp[(((size_t)bb * 16 + hh) * 64 + dd) * 1024 + nn] = f2bf(v);
          }
        } else if (EPI == 1) {
          const float u = v * (0.7978845608f + 0.0356774081f * v * v);
          v = v * __builtin_amdgcn_rcpf(1.0f + __expf(-2.0f * u));
          ((unsigned short*)outp)[(size_t)row * N + col] = f2bf(v);
        } else {
          ((float*)outp)[(size_t)row * N + col] =
              resid[(size_t)row * N + col] + v * lscale;
        }
      }
    }
  }
#undef STG_A
#undef STG_B
#undef RD_AF
#undef RD_BF
#undef MMAQ
#undef PH_SYNC
#undef PH_END
}

// ---------------- flash attention (no 1/sqrt(d) scale, faithful to ref) ----------------
// qk: [16384][2048] bf16 ; vT: [b][h][64 d][1024 n] bf16 ; out: [16384][1024] bf16
__global__ __launch_bounds__(512) void k_attn(const unsigned short* __restrict__ qk,
                                              const unsigned short* __restrict__ vT,
                                              unsigned short* __restrict__ out)
{
  const int qt = blockIdx.x;       // 0..3  (q tile of 256 rows)
  const int bh = blockIdx.y;       // 0..255
  const int b = bh >> 4, h = bh & 15;
  const int t = threadIdx.x, lane = t & 63, wid = t >> 6;
  const int fr = lane & 15, fg = lane >> 4;
  const int q0 = qt * 256 + wid * 32;

  __shared__ __align__(16) unsigned short Ksm[64 * 64];
  __shared__ __align__(16) unsigned short Vsm[64 * 64];
  __shared__ __align__(16) unsigned short plds[8][32][72];

  const size_t qbase = (size_t)b * 1024 * 2048 + (size_t)h * 64;
  const size_t kbase = qbase + 1024;
  const size_t vbase = (size_t)bh * 64 * 1024;

  short8 qf[2][2];
  #pragma unroll
  for (int m = 0; m < 2; m++)
    #pragma unroll
    for (int kh = 0; kh < 2; kh++)
      qf[m][kh] = *(const short8*)(qk + qbase + (size_t)(q0 + m*16 + fr) * 2048
                                   + kh*32 + fg*8);

  f32x4 oacc[2][4] = {};
  float mrow[2][4], lrow[2][4];
  #pragma unroll
  for (int m = 0; m < 2; m++)
    #pragma unroll
    for (int r = 0; r < 4; r++) { mrow[m][r] = -1e30f; lrow[m][r] = 0.f; }

  const int srow = t >> 3, sc = t & 7;
  const int scs = sc ^ (srow & 7);

  for (int kv0 = 0; kv0 < 1024; kv0 += 64) {
    __syncthreads();
    gload16(qk + kbase + (size_t)(kv0 + srow) * 2048 + scs*8, (char*)Ksm + t*16);
    gload16(vT + vbase + (size_t)srow * 1024 + kv0 + scs*8,   (char*)Vsm + t*16);
    __syncthreads();

    f32x4 sacc[2][4] = {};
    #pragma unroll
    for (int n = 0; n < 4; n++) {
      #pragma unroll
      for (int kh = 0; kh < 2; kh++) {
        const int krow = n*16 + fr;
        short8 kf = *(const short8*)&Ksm[krow*64 + (((kh*4 + fg) ^ (krow & 7)) * 8)];
        sacc[0][n] = MFMA16(qf[0][kh], kf, sacc[0][n]);
        sacc[1][n] = MFMA16(qf[1][kh], kf, sacc[1][n]);
      }
    }

    #pragma unroll
    for (int m = 0; m < 2; m++) {
      float pm[4];
      #pragma unroll
      for (int r = 0; r < 4; r++)
        pm[r] = fmaxf(fmaxf(sacc[m][0][r], sacc[m][1][r]),
                      fmaxf(sacc[m][2][r], sacc[m][3][r]));
      #pragma unroll
      for (int msk = 1; msk < 16; msk <<= 1)
        #pragma unroll
        for (int r = 0; r < 4; r++) pm[r] = fmaxf(pm[r], __shfl_xor(pm[r], msk));
      float corr[4];
      #pragma unroll
      for (int r = 0; r < 4; r++) {
        float mn = fmaxf(mrow[m][r], pm[r]);
        corr[r] = __expf(mrow[m][r] - mn);
        mrow[m][r] = mn;
      }
      float psum[4] = {0.f, 0.f, 0.f, 0.f};
      #pragma unroll
      for (int n = 0; n < 4; n++)
        #pragma unroll
        for (int r = 0; r < 4; r++) {
          float p = __expf(sacc[m][n][r] - mrow[m][r]);
          sacc[m][n][r] = p;
          psum[r] += p;
        }
      #pragma unroll
      for (int msk = 1; msk < 16; msk <<= 1)
        #pragma unroll
        for (int r = 0; r < 4; r++) psum[r] += __shfl_xor(psum[r], msk);
      #pragma unroll
      for (int r = 0; r < 4; r++) lrow[m][r] = lrow[m][r] * corr[r] + psum[r];
      #pragma unroll
      for (int d16 = 0; d16 < 4; d16++)
        #pragma unroll
        for (int r = 0; r < 4; r++) oacc[m][d16][r] *= corr[r];
      #pragma unroll
      for (int n = 0; n < 4; n++)
        #pragma unroll
        for (int r = 0; r < 4; r++)
          plds[wid][m*16 + fg*4 + r][n*16 + fr] = f2bf(sacc[m][n][r]);
    }

    short8 pf[2][2];
    #pragma unroll
    for (int m = 0; m < 2; m++)
      #pragma unroll
      for (int kh = 0; kh < 2; kh++)
        pf[m][kh] = *(const short8*)&plds[wid][m*16 + fr][kh*32 + fg*8];

    #pragma unroll
    for (int d16 = 0; d16 < 4; d16++) {
      #pragma unroll
      for (int kh = 0; kh < 2; kh++) {
        const int vrow = d16*16 + fr;
        short8 vf = *(const short8*)&Vsm[vrow*64 + (((kh*4 + fg) ^ (vrow & 7)) * 8)];
        oacc[0][d16] = MFMA16(pf[0][kh], vf, oacc[0][d16]);
        oacc[1][d16] = MFMA16(pf[1][kh], vf, oacc[1][d16]);
      }
    }
  }

  #pragma unroll
  for (int m = 0; m < 2; m++) {
    float inv[4];
    #pragma unroll
    for (int r = 0; r < 4; r++) inv[r] = 1.0f / lrow[m][r];
    #pragma unroll
    for (int d16 = 0; d16 < 4; d16++) {
      #pragma unroll
      for (int r = 0; r < 4; r++) {
        const int qrow = q0 + m*16 + fg*4 + r;
        const int col = h*64 + d16*16 + fr;
        out[(size_t)(b * 1024 + qrow) * 1024 + col] = f2bf(oacc[m][d16][r] * inv[r]);
      }
    }
  }
}

// ---------------- host launch ----------------
extern "C" void kernel_launch(void* const* d_in, const int* in_sizes, int n_in,
                              void* d_out, int out_size, void* d_ws, size_t ws_size,
                              hipStream_t stream) {
  const float* x      = (const float*)d_in[0];
  const float* ln1_g  = (const float*)d_in[1];
  const float* ln1_b  = (const float*)d_in[2];
  const float* qkv_w  = (const float*)d_in[3];
  const float* qkv_b  = (const float*)d_in[4];
  const float* proj_w = (const float*)d_in[5];
  const float* proj_b = (const float*)d_in[6];
  const float* ls1_g  = (const float*)d_in[7];
  const float* ln2_g  = (const float*)d_in[8];
  const float* ln2_b  = (const float*)d_in[9];
  const float* fc1_w  = (const float*)d_in[10];
  const float* fc1_b  = (const float*)d_in[11];
  const float* fc2_w  = (const float*)d_in[12];
  const float* fc2_b  = (const float*)d_in[13];
  const float* ls2_g  = (const float*)d_in[14];

  char* w = (char*)d_ws;
  unsigned short* wqkvT  = (unsigned short*)(w + 0);                    //  6,291,456
  unsigned short* wprojT = (unsigned short*)(w + 6291456);              //  2,097,152
  unsigned short* wfc1T  = (unsigned short*)(w + 8388608);              //  8,388,608
  unsigned short* wfc2T  = (unsigned short*)(w + 16777216);             //  8,388,608
  float*          x1     = (float*)(w + 25165824);                      // 67,108,864
  unsigned short* h1     = (unsigned short*)(w + 92274688);             // 33,554,432 (reused as h2)
  unsigned short* qkbuf  = (unsigned short*)(w + 125829120);            // 67,108,864 [16384][2048]
  unsigned short* vtbuf  = (unsigned short*)(w + 192937984);            // 33,554,432 [256][64][1024]
  unsigned short* attno  = (unsigned short*)(w + 226492416);            // 33,554,432
  unsigned short* h3     = (unsigned short*)(w + 125829120);            // 134,217,728 (overlays qk+vT)

  dim3 tb32(32, 8);
  k_transpose_cast<<<dim3(3072/32, 1024/32), tb32, 0, stream>>>(qkv_w,  wqkvT, 1024, 3072);
  k_transpose_cast<<<dim3(1024/32, 1024/32), tb32, 0, stream>>>(proj_w, wprojT, 1024, 1024);
  k_transpose_cast<<<dim3(4096/32, 1024/32), tb32, 0, stream>>>(fc1_w,  wfc1T, 1024, 4096);
  k_transpose_cast<<<dim3(1024/32, 4096/32), tb32, 0, stream>>>(fc2_w,  wfc2T, 4096, 1024);

  // LN1
  k_layernorm<<<16384, 256, 0, stream>>>(x, ln1_g, ln1_b, h1);
  // QKV = h1 @ qkv_w + qkv_b ; Q,K -> qkbuf, V -> vtbuf transposed
  k_gemm256<0><<<64*12, 512, 0, stream>>>(h1, wqkvT, qkv_b, nullptr, nullptr,
                                          qkbuf, vtbuf, 16384, 3072, 1024, 12);
  // attention
  k_attn<<<dim3(4, 256), 512, 0, stream>>>(qkbuf, vtbuf, attno);
  // x1 = x + (attn @ proj_w + proj_b) * ls1_g
  k_gemm256<2><<<64*4, 512, 0, stream>>>(attno, wprojT, proj_b, x, ls1_g,
                                         x1, nullptr, 16384, 1024, 1024, 4);
  // LN2
  k_layernorm<<<16384, 256, 0, stream>>>(x1, ln2_g, ln2_b, h1);
  // h3 = gelu(h2 @ fc1_w + fc1_b)
  k_gemm256<1><<<64*16, 512, 0, stream>>>(h1, wfc1T, fc1_b, nullptr, nullptr,
                                          h3, nullptr, 16384, 4096, 1024, 16);
  // out = x1 + (h3 @ fc2_w + fc2_b) * ls2_g
  k_gemm256<2><<<64*4, 512, 0, stream>>>(h3, wfc2T, fc2_b, x1, ls2_g,
                                         (float*)d_out, nullptr, 16384, 1024, 4096, 4);
}